// Round 2
// baseline (2127.627 us; speedup 1.0000x reference)
//
#include <hip/hip_runtime.h>

typedef unsigned short u16;
typedef __attribute__((ext_vector_type(8))) short bf16x8;
typedef __attribute__((ext_vector_type(4))) float f32x4;

#define LSTR 40  // LDS row stride (32 + 8 pad), elems

__device__ __forceinline__ u16 f2bf(float f) {
  union { float f; unsigned u; } v; v.f = f;
  unsigned r = (v.u + 0x7fffu + ((v.u >> 16) & 1u)) >> 16;
  return (u16)r;
}
__device__ __forceinline__ float bf2f(u16 u) {
  union { unsigned u; float f; } v; v.u = ((unsigned)u) << 16;
  return v.f;
}
__device__ __forceinline__ void split2(float f, u16& hi, u16& lo) {
  hi = f2bf(f);
  lo = f2bf(f - bf2f(hi));
}

// ---------------- bf16 staging (MoE path) -----------------------------------
__device__ __forceinline__ void stage_rows_bf16(u16* __restrict__ s,
    const u16* __restrict__ g, long ld, int k0, int rowsValid, int tid) {
#pragma unroll
  for (int u = tid; u < 512; u += 256) {
    int r = u >> 2, c = (u & 3) << 3;
    uint4 v = make_uint4(0, 0, 0, 0);
    if (r < rowsValid) v = *reinterpret_cast<const uint4*>(g + (long)r * ld + k0 + c);
    *reinterpret_cast<uint4*>(&s[r * LSTR + c]) = v;
  }
}

__device__ __forceinline__ void stage_rows_gather(u16* __restrict__ s,
    const u16* __restrict__ base, const int* __restrict__ rows, int rowsValid,
    int k0, int tid) {
#pragma unroll
  for (int u = tid; u < 512; u += 256) {
    int r = u >> 2, c = (u & 3) << 3;
    uint4 v = make_uint4(0, 0, 0, 0);
    if (r < rowsValid) {
      long row = rows[r];
      v = *reinterpret_cast<const uint4*>(base + row * 2048 + k0 + c);
    }
    *reinterpret_cast<uint4*>(&s[r * LSTR + c]) = v;
  }
}

// fp32 B[k][n] (row-major, ld=N) -> LDS [n][k] bf16, tile 32k x 128n
__device__ __forceinline__ void stage_B_nn(u16* __restrict__ s,
    const float* __restrict__ B, long ld, int k0, int tid) {
  int n4 = (tid & 31) << 2, k4 = (tid >> 5) << 2;
  const float* p = B + (long)(k0 + k4) * ld + n4;
  float rr[4][4];
  *reinterpret_cast<float4*>(rr[0]) = *reinterpret_cast<const float4*>(p);
  *reinterpret_cast<float4*>(rr[1]) = *reinterpret_cast<const float4*>(p + ld);
  *reinterpret_cast<float4*>(rr[2]) = *reinterpret_cast<const float4*>(p + 2 * ld);
  *reinterpret_cast<float4*>(rr[3]) = *reinterpret_cast<const float4*>(p + 3 * ld);
#pragma unroll
  for (int j = 0; j < 4; j++) {
    ushort4 o;
    o.x = f2bf(rr[0][j]); o.y = f2bf(rr[1][j]);
    o.z = f2bf(rr[2][j]); o.w = f2bf(rr[3][j]);
    *reinterpret_cast<ushort4*>(&s[(n4 + j) * LSTR + k4]) = o;
  }
}

// ---------------- split (hi/lo) staging --------------------------------------
// fp32 rows [r][k] -> hi/lo bf16 LDS tiles, 128 rows x 32 cols
__device__ __forceinline__ void stage_rows_split(u16* __restrict__ sHi,
    u16* __restrict__ sLo, const float* __restrict__ g, long ld, int k0, int tid) {
#pragma unroll
  for (int u = tid; u < 512; u += 256) {
    int r = u >> 2, c = (u & 3) << 3;
    const float* p = g + (long)r * ld + k0 + c;
    float4 v0 = *reinterpret_cast<const float4*>(p);
    float4 v1 = *reinterpret_cast<const float4*>(p + 4);
    float f[8] = {v0.x, v0.y, v0.z, v0.w, v1.x, v1.y, v1.z, v1.w};
    u16 h[8], l[8];
#pragma unroll
    for (int i = 0; i < 8; i++) split2(f[i], h[i], l[i]);
    *reinterpret_cast<uint4*>(&sHi[r * LSTR + c]) = *reinterpret_cast<uint4*>(h);
    *reinterpret_cast<uint4*>(&sLo[r * LSTR + c]) = *reinterpret_cast<uint4*>(l);
  }
}

// fp32 B[k][n] (ld=N) -> hi/lo LDS [n][k], tile 32k x 128n
__device__ __forceinline__ void stage_B_nn_split(u16* __restrict__ sHi,
    u16* __restrict__ sLo, const float* __restrict__ B, long ld, int k0, int tid) {
  int n4 = (tid & 31) << 2, k4 = (tid >> 5) << 2;
  const float* p = B + (long)(k0 + k4) * ld + n4;
  float rr[4][4];
  *reinterpret_cast<float4*>(rr[0]) = *reinterpret_cast<const float4*>(p);
  *reinterpret_cast<float4*>(rr[1]) = *reinterpret_cast<const float4*>(p + ld);
  *reinterpret_cast<float4*>(rr[2]) = *reinterpret_cast<const float4*>(p + 2 * ld);
  *reinterpret_cast<float4*>(rr[3]) = *reinterpret_cast<const float4*>(p + 3 * ld);
#pragma unroll
  for (int j = 0; j < 4; j++) {
    ushort4 oh, ol;
    u16 h, l;
    split2(rr[0][j], h, l); oh.x = h; ol.x = l;
    split2(rr[1][j], h, l); oh.y = h; ol.y = l;
    split2(rr[2][j], h, l); oh.z = h; ol.z = l;
    split2(rr[3][j], h, l); oh.w = h; ol.w = l;
    *reinterpret_cast<ushort4*>(&sHi[(n4 + j) * LSTR + k4]) = oh;
    *reinterpret_cast<ushort4*>(&sLo[(n4 + j) * LSTR + k4]) = ol;
  }
}

// ---------------- MFMA cores --------------------------------------------------
__device__ __forceinline__ void mfma_step(const u16* __restrict__ sA,
    const u16* __restrict__ sB, f32x4 (&acc)[4][4], int wm, int wn, int lr, int lk) {
  bf16x8 a[4], b[4];
#pragma unroll
  for (int i = 0; i < 4; i++)
    a[i] = *reinterpret_cast<const bf16x8*>(&sA[(wm + i * 16 + lr) * LSTR + lk]);
#pragma unroll
  for (int i = 0; i < 4; i++)
    b[i] = *reinterpret_cast<const bf16x8*>(&sB[(wn + i * 16 + lr) * LSTR + lk]);
#pragma unroll
  for (int i = 0; i < 4; i++)
#pragma unroll
    for (int j = 0; j < 4; j++)
      acc[i][j] = __builtin_amdgcn_mfma_f32_16x16x32_bf16(a[i], b[j], acc[i][j], 0, 0, 0);
}

__device__ __forceinline__ void mfma_step_split(const u16* __restrict__ sAhi,
    const u16* __restrict__ sAlo, const u16* __restrict__ sBhi,
    const u16* __restrict__ sBlo, f32x4 (&acc)[4][4], int wm, int wn, int lr, int lk) {
  bf16x8 ah[4], al[4], bh[4], bl[4];
#pragma unroll
  for (int i = 0; i < 4; i++) {
    ah[i] = *reinterpret_cast<const bf16x8*>(&sAhi[(wm + i * 16 + lr) * LSTR + lk]);
    al[i] = *reinterpret_cast<const bf16x8*>(&sAlo[(wm + i * 16 + lr) * LSTR + lk]);
  }
#pragma unroll
  for (int i = 0; i < 4; i++) {
    bh[i] = *reinterpret_cast<const bf16x8*>(&sBhi[(wn + i * 16 + lr) * LSTR + lk]);
    bl[i] = *reinterpret_cast<const bf16x8*>(&sBlo[(wn + i * 16 + lr) * LSTR + lk]);
  }
#pragma unroll
  for (int i = 0; i < 4; i++)
#pragma unroll
    for (int j = 0; j < 4; j++) {
      f32x4 t = acc[i][j];
      t = __builtin_amdgcn_mfma_f32_16x16x32_bf16(al[i], bl[j], t, 0, 0, 0);
      t = __builtin_amdgcn_mfma_f32_16x16x32_bf16(al[i], bh[j], t, 0, 0, 0);
      t = __builtin_amdgcn_mfma_f32_16x16x32_bf16(ah[i], bl[j], t, 0, 0, 0);
      t = __builtin_amdgcn_mfma_f32_16x16x32_bf16(ah[i], bh[j], t, 0, 0, 0);
      acc[i][j] = t;
    }
}

#define GEMM_PREAMBLE \
  __shared__ __align__(16) u16 sA[128 * LSTR]; \
  __shared__ __align__(16) u16 sB[128 * LSTR]; \
  int tid = threadIdx.x; \
  int lane = tid & 63; \
  int wm = ((tid >> 6) & 1) * 64, wn = (tid >> 7) * 64; \
  int lr = lane & 15, lk = (lane >> 4) << 3; \
  int er = (lane >> 4) << 2, ec = lane & 15; \
  f32x4 acc[4][4] = {};

#define SPLIT_PREAMBLE \
  __shared__ __align__(16) u16 sAhi[128 * LSTR]; \
  __shared__ __align__(16) u16 sAlo[128 * LSTR]; \
  __shared__ __align__(16) u16 sBhi[128 * LSTR]; \
  __shared__ __align__(16) u16 sBlo[128 * LSTR]; \
  int tid = threadIdx.x; \
  int lane = tid & 63; \
  int wm = ((tid >> 6) & 1) * 64, wn = (tid >> 7) * 64; \
  int lr = lane & 15, lk = (lane >> 4) << 3; \
  int er = (lane >> 4) << 2, ec = lane & 15; \
  f32x4 acc[4][4] = {};

// ---------------- elementwise / small kernels -------------------------------

// rmsnorm row (D=2048 fp32) -> fp32
__global__ __launch_bounds__(256) void rmsnorm_f32(const float* __restrict__ x,
    const float* __restrict__ w, float* __restrict__ o) {
  __shared__ float lbuf[4];
  int tid = threadIdx.x;
  long base = (long)blockIdx.x * 2048;
  float4 v0 = *reinterpret_cast<const float4*>(&x[base + tid * 8]);
  float4 v1 = *reinterpret_cast<const float4*>(&x[base + tid * 8 + 4]);
  float ss = v0.x * v0.x + v0.y * v0.y + v0.z * v0.z + v0.w * v0.w +
             v1.x * v1.x + v1.y * v1.y + v1.z * v1.z + v1.w * v1.w;
  for (int off = 32; off; off >>= 1) ss += __shfl_down(ss, off);
  if ((tid & 63) == 0) lbuf[tid >> 6] = ss;
  __syncthreads();
  float tot = lbuf[0] + lbuf[1] + lbuf[2] + lbuf[3];
  float scale = 1.0f / sqrtf(tot * (1.0f / 2048.0f) + 1e-6f);
  float4 w0 = *reinterpret_cast<const float4*>(&w[tid * 8]);
  float4 w1 = *reinterpret_cast<const float4*>(&w[tid * 8 + 4]);
  float4 o0, o1;
  o0.x = v0.x * scale * w0.x; o0.y = v0.y * scale * w0.y;
  o0.z = v0.z * scale * w0.z; o0.w = v0.w * scale * w0.w;
  o1.x = v1.x * scale * w1.x; o1.y = v1.y * scale * w1.y;
  o1.z = v1.z * scale * w1.z; o1.w = v1.w * scale * w1.w;
  *reinterpret_cast<float4*>(&o[base + tid * 8]) = o0;
  *reinterpret_cast<float4*>(&o[base + tid * 8 + 4]) = o1;
}

// rmsnorm row -> bf16 (MoE input)
__global__ __launch_bounds__(256) void rmsnorm_bf16(const float* __restrict__ x,
    const float* __restrict__ w, u16* __restrict__ o) {
  __shared__ float lbuf[4];
  int tid = threadIdx.x;
  long base = (long)blockIdx.x * 2048;
  float4 v0 = *reinterpret_cast<const float4*>(&x[base + tid * 8]);
  float4 v1 = *reinterpret_cast<const float4*>(&x[base + tid * 8 + 4]);
  float ss = v0.x * v0.x + v0.y * v0.y + v0.z * v0.z + v0.w * v0.w +
             v1.x * v1.x + v1.y * v1.y + v1.z * v1.z + v1.w * v1.w;
  for (int off = 32; off; off >>= 1) ss += __shfl_down(ss, off);
  if ((tid & 63) == 0) lbuf[tid >> 6] = ss;
  __syncthreads();
  float tot = lbuf[0] + lbuf[1] + lbuf[2] + lbuf[3];
  float scale = 1.0f / sqrtf(tot * (1.0f / 2048.0f) + 1e-6f);
  float4 w0 = *reinterpret_cast<const float4*>(&w[tid * 8]);
  float4 w1 = *reinterpret_cast<const float4*>(&w[tid * 8 + 4]);
  ushort4 o0, o1;
  o0.x = f2bf(v0.x * scale * w0.x); o0.y = f2bf(v0.y * scale * w0.y);
  o0.z = f2bf(v0.z * scale * w0.z); o0.w = f2bf(v0.w * scale * w0.w);
  o1.x = f2bf(v1.x * scale * w1.x); o1.y = f2bf(v1.y * scale * w1.y);
  o1.z = f2bf(v1.z * scale * w1.z); o1.w = f2bf(v1.w * scale * w1.w);
  *reinterpret_cast<ushort4*>(&o[base + tid * 8]) = o0;
  *reinterpret_cast<ushort4*>(&o[base + tid * 8 + 4]) = o1;
}

// in-place RoPE on fp32 [b][s][nh][128]; one 64-lane unit per (b,s,head)
__global__ __launch_bounds__(256) void rope_f32(float* __restrict__ x, int nh) {
  int unit = blockIdx.x * 4 + (threadIdx.x >> 6);
  int lane = threadIdx.x & 63;
  int s = (unit / nh) & 1023;
  float* p = x + (long)unit * 128;
  float x1 = p[lane], x2 = p[lane + 64];
  float ang = (float)s * exp2f((float)lane * (-13.287712379549449f / 64.0f));
  float sn, cs;
  sincosf(ang, &sn, &cs);
  p[lane] = x1 * cs - x2 * sn;
  p[lane + 64] = x1 * sn + x2 * cs;
}

// fp32 transpose [R][C] -> [C][R] per batch (blockIdx.z)
__global__ __launch_bounds__(256) void transpose_f32(const float* __restrict__ in,
    float* __restrict__ out, int R, int C) {
  __shared__ float tile[32][33];
  long bo = (long)blockIdx.z * R * C;
  int r0 = blockIdx.y * 32, c0 = blockIdx.x * 32;
  int r = threadIdx.x >> 5, c = threadIdx.x & 31;
#pragma unroll
  for (int i = 0; i < 4; i++)
    tile[r + i * 8][c] = in[bo + (long)(r0 + r + i * 8) * C + c0 + c];
  __syncthreads();
#pragma unroll
  for (int i = 0; i < 4; i++)
    out[bo + (long)(c0 + r + i * 8) * R + r0 + c] = tile[c][r + i * 8];
}

// causal softmax in-place on fp32 scores row (len 1024); slab row = bhloc*1024+q
__global__ __launch_bounds__(256) void softmax_f32(float* __restrict__ sc) {
  __shared__ float lbuf[4];
  long row = blockIdx.x;
  int q = (int)(row & 1023);
  float* p = sc + row * 1024;
  int tid = threadIdx.x;
  int valid = q + 1;
  int pend = (q & ~127) + 128;
  float v[4];
  float mx = -1e30f;
#pragma unroll
  for (int i = 0; i < 4; i++) {
    int t = tid + i * 256;
    float f = (t < valid) ? p[t] : -1e30f;
    v[i] = f;
    mx = fmaxf(mx, f);
  }
  for (int off = 32; off; off >>= 1) mx = fmaxf(mx, __shfl_down(mx, off));
  if ((tid & 63) == 0) lbuf[tid >> 6] = mx;
  __syncthreads();
  float m = fmaxf(fmaxf(lbuf[0], lbuf[1]), fmaxf(lbuf[2], lbuf[3]));
  __syncthreads();
  float sum = 0.0f;
#pragma unroll
  for (int i = 0; i < 4; i++) {
    int t = tid + i * 256;
    float e = (t < valid) ? expf(v[i] - m) : 0.0f;
    v[i] = e;
    sum += e;
  }
  for (int off = 32; off; off >>= 1) sum += __shfl_down(sum, off);
  if ((tid & 63) == 0) lbuf[tid >> 6] = sum;
  __syncthreads();
  float inv = 1.0f / (lbuf[0] + lbuf[1] + lbuf[2] + lbuf[3]);
#pragma unroll
  for (int i = 0; i < 4; i++) {
    int t = tid + i * 256;
    if (t < valid) p[t] = v[i] * inv;
    else if (t < pend) p[t] = 0.0f;
  }
}

// router: fp32 rmsnorm of out row + fp32 logits, top-2, gates, counts
__global__ __launch_bounds__(256) void router_kernel(const float* __restrict__ xo,
    const float* __restrict__ w, const float* __restrict__ Wr,
    int* __restrict__ tok_e, float* __restrict__ tok_g, int* __restrict__ counts) {
  __shared__ float lbuf[32];
  int tid = threadIdx.x;
  long base = (long)blockIdx.x * 2048;
  float4 v0 = *reinterpret_cast<const float4*>(&xo[base + tid * 8]);
  float4 v1 = *reinterpret_cast<const float4*>(&xo[base + tid * 8 + 4]);
  float ss = v0.x * v0.x + v0.y * v0.y + v0.z * v0.z + v0.w * v0.w +
             v1.x * v1.x + v1.y * v1.y + v1.z * v1.z + v1.w * v1.w;
  for (int off = 32; off; off >>= 1) ss += __shfl_down(ss, off);
  if ((tid & 63) == 0) lbuf[tid >> 6] = ss;
  __syncthreads();
  float tot = lbuf[0] + lbuf[1] + lbuf[2] + lbuf[3];
  float scale = 1.0f / sqrtf(tot * (1.0f / 2048.0f) + 1e-6f);
  __syncthreads();
  float4 w0 = *reinterpret_cast<const float4*>(&w[tid * 8]);
  float4 w1 = *reinterpret_cast<const float4*>(&w[tid * 8 + 4]);
  float h[8] = {v0.x * scale * w0.x, v0.y * scale * w0.y, v0.z * scale * w0.z,
                v0.w * scale * w0.w, v1.x * scale * w1.x, v1.y * scale * w1.y,
                v1.z * scale * w1.z, v1.w * scale * w1.w};
  float part[8] = {0, 0, 0, 0, 0, 0, 0, 0};
#pragma unroll
  for (int j = 0; j < 8; j++) {
    const float* wr = Wr + (long)(tid * 8 + j) * 8;
    float4 a = *reinterpret_cast<const float4*>(wr);
    float4 b = *reinterpret_cast<const float4*>(wr + 4);
    part[0] += h[j] * a.x; part[1] += h[j] * a.y;
    part[2] += h[j] * a.z; part[3] += h[j] * a.w;
    part[4] += h[j] * b.x; part[5] += h[j] * b.y;
    part[6] += h[j] * b.z; part[7] += h[j] * b.w;
  }
#pragma unroll
  for (int e = 0; e < 8; e++) {
    float s = part[e];
    for (int off = 32; off; off >>= 1) s += __shfl_down(s, off);
    if ((tid & 63) == 0) lbuf[(tid >> 6) * 8 + e] = s;
  }
  __syncthreads();
  if (tid == 0) {
    float lg[8];
#pragma unroll
    for (int e = 0; e < 8; e++)
      lg[e] = lbuf[e] + lbuf[8 + e] + lbuf[16 + e] + lbuf[24 + e];
    int e1 = 0;
    for (int e = 1; e < 8; e++) if (lg[e] > lg[e1]) e1 = e;
    int e2 = -1;
    for (int e = 0; e < 8; e++) if (e != e1 && (e2 < 0 || lg[e] > lg[e2])) e2 = e;
    float ex = __expf(lg[e2] - lg[e1]);
    float g1 = 1.0f / (1.0f + ex);
    tok_e[blockIdx.x * 2] = e1; tok_e[blockIdx.x * 2 + 1] = e2;
    tok_g[blockIdx.x * 2] = g1; tok_g[blockIdx.x * 2 + 1] = 1.0f - g1;
    atomicAdd(&counts[e1], 1);
    atomicAdd(&counts[e2], 1);
  }
}

__global__ void scan8(const int* __restrict__ counts, int* __restrict__ offsets,
                      int* __restrict__ cursor) {
  if (threadIdx.x == 0) {
    int off = 0;
    for (int e = 0; e < 8; e++) { offsets[e] = off; off += counts[e]; cursor[e] = 0; }
  }
}

__global__ __launch_bounds__(256) void fill_lists(const int* __restrict__ tok_e,
    const float* __restrict__ tok_g, const int* __restrict__ offsets,
    int* __restrict__ cursor, int* __restrict__ ltok, float* __restrict__ lgate) {
  int idx = blockIdx.x * 256 + threadIdx.x;  // 4096 slots
  int token = idx >> 1;
  int e = tok_e[idx];
  float g = tok_g[idx];
  int pos = atomicAdd(&cursor[e], 1);
  int j = offsets[e] + pos;
  ltok[j] = token;
  lgate[j] = g;
}

// ---------------- split GEMM kernels (attention path, fp32 I/O) -------------

// C[M][N] = A[M][K] * B[K][N] (+ resid)
__global__ __launch_bounds__(256) void gemm_nn_split(const float* __restrict__ A,
    const float* __restrict__ B, const float* __restrict__ resid,
    float* __restrict__ C, int M, int N, int K) {
  SPLIT_PREAMBLE
  int m0 = blockIdx.y * 128, n0 = blockIdx.x * 128;
  const float* Ab = A + (long)m0 * K;
  const float* Bb = B + n0;
  for (int k0 = 0; k0 < K; k0 += 32) {
    __syncthreads();
    stage_rows_split(sAhi, sAlo, Ab, K, k0, tid);
    stage_B_nn_split(sBhi, sBlo, Bb, N, k0, tid);
    __syncthreads();
    mfma_step_split(sAhi, sAlo, sBhi, sBlo, acc, wm, wn, lr, lk);
  }
#pragma unroll
  for (int i = 0; i < 4; i++)
#pragma unroll
    for (int j = 0; j < 4; j++)
#pragma unroll
      for (int r = 0; r < 4; r++) {
        long idx = (long)(m0 + wm + i * 16 + er + r) * N + n0 + wn + j * 16 + ec;
        float v = acc[i][j][r];
        C[idx] = resid ? resid[idx] + v : v;
      }
}

// scores slab: [bhloc][q][t] = (q . k) * DK^-0.5, lower-triangular tile grid
__global__ __launch_bounds__(256) void gemm_qk_split(const float* __restrict__ q,
    const float* __restrict__ kk, float* __restrict__ sc, int bh0) {
  SPLIT_PREAMBLE
  int idx = blockIdx.x, mi = 0;
  while ((mi + 1) * (mi + 2) / 2 <= idx) mi++;
  int ni = idx - mi * (mi + 1) / 2;
  int bh = bh0 + blockIdx.y, b = bh >> 4, h = bh & 15, g = h >> 2;
  int m0 = mi * 128, n0 = ni * 128;
  const float* Ab = q + ((long)(b * 1024) * 16 + h) * 128 + (long)m0 * 2048;
  const float* Bb = kk + ((long)(b * 1024) * 4 + g) * 128 + (long)n0 * 512;
  float* Cb = sc + ((long)blockIdx.y * 1024 + m0) * 1024 + n0;
  for (int k0 = 0; k0 < 128; k0 += 32) {
    __syncthreads();
    stage_rows_split(sAhi, sAlo, Ab, 2048, k0, tid);
    stage_rows_split(sBhi, sBlo, Bb, 512, k0, tid);
    __syncthreads();
    mfma_step_split(sAhi, sAlo, sBhi, sBlo, acc, wm, wn, lr, lk);
  }
  const float scalef = 0.08838834764831845f;
#pragma unroll
  for (int i = 0; i < 4; i++)
#pragma unroll
    for (int j = 0; j < 4; j++)
#pragma unroll
      for (int r = 0; r < 4; r++) {
        int row = wm + i * 16 + er + r, col = wn + j * 16 + ec;
        Cb[(long)row * 1024 + col] = acc[i][j][r] * scalef;
      }
}

// attn[b][q][h][dv] = probs @ v  (B = vT[b][g][dv][t], causal K-limit)
__global__ __launch_bounds__(256) void gemm_pv_split(const float* __restrict__ probs,
    const float* __restrict__ vT, float* __restrict__ attn, int bh0) {
  SPLIT_PREAMBLE
  int m0 = blockIdx.x * 128;
  int bh = bh0 + blockIdx.y, b = bh >> 4, h = bh & 15, g = h >> 2;
  const float* Ab = probs + (long)blockIdx.y * 1024 * 1024 + (long)m0 * 1024;
  const float* Bb = vT + (long)(b * 4 + g) * 128 * 1024;
  float* Cb = attn + ((long)(b * 1024 + m0) * 16 + h) * 128;
  int Klim = m0 + 128;
  for (int k0 = 0; k0 < Klim; k0 += 32) {
    __syncthreads();
    stage_rows_split(sAhi, sAlo, Ab, 1024, k0, tid);
    stage_rows_split(sBhi, sBlo, Bb, 1024, k0, tid);
    __syncthreads();
    mfma_step_split(sAhi, sAlo, sBhi, sBlo, acc, wm, wn, lr, lk);
  }
#pragma unroll
  for (int i = 0; i < 4; i++)
#pragma unroll
    for (int j = 0; j < 4; j++)
#pragma unroll
      for (int r = 0; r < 4; r++) {
        int row = wm + i * 16 + er + r, col = wn + j * 16 + ec;
        Cb[(long)row * 2048 + col] = acc[i][j][r];
      }
}

// ---------------- bf16 MoE GEMMs --------------------------------------------

// mid[slot][F] = silu(gather(t2) @ W1[e])
__global__ __launch_bounds__(256) void gemm_moe1(const u16* __restrict__ t2,
    const float* __restrict__ W1, const int* __restrict__ offsets,
    const int* __restrict__ counts, const int* __restrict__ ltok,
    u16* __restrict__ mid) {
  int e = blockIdx.z;
  int cnt = counts[e];
  int m0 = blockIdx.y * 128;
  if (m0 >= cnt) return;
  GEMM_PREAMBLE
  int off = offsets[e];
  int n0 = blockIdx.x * 128;
  int valid = cnt - m0; if (valid > 128) valid = 128;
  const int* rows = ltok + off + m0;
  const float* Bb = W1 + (long)e * 2048 * 4096 + n0;
  for (int k0 = 0; k0 < 2048; k0 += 32) {
    __syncthreads();
    stage_rows_gather(sA, t2, rows, valid, k0, tid);
    stage_B_nn(sB, Bb, 4096, k0, tid);
    __syncthreads();
    mfma_step(sA, sB, acc, wm, wn, lr, lk);
  }
#pragma unroll
  for (int i = 0; i < 4; i++)
#pragma unroll
    for (int j = 0; j < 4; j++)
#pragma unroll
      for (int r = 0; r < 4; r++) {
        int rowl = wm + i * 16 + er + r;
        if (rowl < valid) {
          float v = acc[i][j][r];
          v = v / (1.0f + __expf(-v));
          mid[(long)(off + m0 + rowl) * 4096 + n0 + wn + j * 16 + ec] = f2bf(v);
        }
      }
}

// out[token] += gate * (mid @ W2[e])
__global__ __launch_bounds__(256) void gemm_moe2(const u16* __restrict__ mid,
    const float* __restrict__ W2, const int* __restrict__ offsets,
    const int* __restrict__ counts, const int* __restrict__ ltok,
    const float* __restrict__ lgate, float* __restrict__ out) {
  int e = blockIdx.z;
  int cnt = counts[e];
  int m0 = blockIdx.y * 128;
  if (m0 >= cnt) return;
  GEMM_PREAMBLE
  int off = offsets[e];
  int n0 = blockIdx.x * 128;
  int valid = cnt - m0; if (valid > 128) valid = 128;
  const u16* Ab = mid + (long)(off + m0) * 4096;
  const float* Bb = W2 + (long)e * 4096 * 2048 + n0;
  for (int k0 = 0; k0 < 4096; k0 += 32) {
    __syncthreads();
    stage_rows_bf16(sA, Ab, 4096, k0, valid, tid);
    stage_B_nn(sB, Bb, 2048, k0, tid);
    __syncthreads();
    mfma_step(sA, sB, acc, wm, wn, lr, lk);
  }
#pragma unroll
  for (int i = 0; i < 4; i++)
#pragma unroll
    for (int j = 0; j < 4; j++)
#pragma unroll
      for (int r = 0; r < 4; r++) {
        int rowl = wm + i * 16 + er + r;
        if (rowl < valid) {
          int t = ltok[off + m0 + rowl];
          float g = lgate[off + m0 + rowl];
          atomicAdd(&out[(long)t * 2048 + n0 + wn + j * 16 + ec], g * acc[i][j][r]);
        }
      }
}

// ---------------- launch -----------------------------------------------------
extern "C" void kernel_launch(void* const* d_in, const int* in_sizes, int n_in,
                              void* d_out, int out_size, void* d_ws, size_t ws_size,
                              hipStream_t stream) {
  (void)in_sizes; (void)n_in; (void)out_size; (void)ws_size;
  const float* x   = (const float*)d_in[0];
  const float* ln1 = (const float*)d_in[1];
  const float* Wq  = (const float*)d_in[2];
  const float* Wk  = (const float*)d_in[3];
  const float* Wv  = (const float*)d_in[4];
  const float* Wo  = (const float*)d_in[5];
  const float* ln2 = (const float*)d_in[6];
  const float* Wr  = (const float*)d_in[7];
  const float* W1  = (const float*)d_in[8];
  const float* W2  = (const float*)d_in[9];
  float* out = (float*)d_out;
  char* ws = (char*)d_ws;

  // ws layout (total ~138.5 MB)
  float* h    = (float*)(ws);                 // 16.78 MB
  float* q    = (float*)(ws + 16777216);      // 16.78 MB
  float* kk   = (float*)(ws + 33554432);      //  4.19 MB
  float* vv   = (float*)(ws + 37748736);      //  4.19 MB
  float* vT   = (float*)(ws + 41943040);      //  4.19 MB
  float* attn = (float*)(ws + 46137344);      // 16.78 MB
  u16*   t2   = (u16*)  (ws + 62914560);      //  8.39 MB
  float* sc   = (float*)(ws + 71303168);      // 33.55 MB (8-head slab, fp32)
  u16*   mid  = (u16*)  (ws + 104857600);     // 33.55 MB
  char* misc = ws + 138412032;
  int*   tok_e   = (int*)misc;
  float* tok_g   = (float*)(misc + 16384);
  int*   ltok    = (int*)(misc + 32768);
  float* lgate   = (float*)(misc + 49152);
  int*   counts  = (int*)(misc + 65536);
  int*   offsets = (int*)(misc + 65568);
  int*   cursor  = (int*)(misc + 65600);

  rmsnorm_f32<<<2048, 256, 0, stream>>>(x, ln1, h);
  gemm_nn_split<<<dim3(16, 16), 256, 0, stream>>>(h, Wq, nullptr, q, 2048, 2048, 2048);
  gemm_nn_split<<<dim3(4, 16), 256, 0, stream>>>(h, Wk, nullptr, kk, 2048, 512, 2048);
  gemm_nn_split<<<dim3(4, 16), 256, 0, stream>>>(h, Wv, nullptr, vv, 2048, 512, 2048);
  rope_f32<<<8192, 256, 0, stream>>>(q, 16);
  rope_f32<<<2048, 256, 0, stream>>>(kk, 4);
  transpose_f32<<<dim3(16, 32, 2), 256, 0, stream>>>(vv, vT, 1024, 512);
  for (int s = 0; s < 4; s++) {
    gemm_qk_split<<<dim3(36, 8), 256, 0, stream>>>(q, kk, sc, s * 8);
    softmax_f32<<<8192, 256, 0, stream>>>(sc);
    gemm_pv_split<<<dim3(8, 8), 256, 0, stream>>>(sc, vT, attn, s * 8);
  }
  gemm_nn_split<<<dim3(16, 16), 256, 0, stream>>>(attn, Wo, x, out, 2048, 2048, 2048);
  rmsnorm_bf16<<<2048, 256, 0, stream>>>(out, ln2, t2);
  hipMemsetAsync(counts, 0, 32, stream);
  router_kernel<<<2048, 256, 0, stream>>>(out, ln2, Wr, tok_e, tok_g, counts);
  scan8<<<1, 64, 0, stream>>>(counts, offsets, cursor);
  fill_lists<<<16, 256, 0, stream>>>(tok_e, tok_g, offsets, cursor, ltok, lgate);
  gemm_moe1<<<dim3(32, 16, 8), 256, 0, stream>>>(t2, W1, offsets, counts, ltok, mid);
  gemm_moe2<<<dim3(16, 16, 8), 256, 0, stream>>>(mid, W2, offsets, counts, ltok, lgate, out);
}